// Round 2
// baseline (1560.058 us; speedup 1.0000x reference)
//
#include <hip/hip_runtime.h>
#include <hip/hip_bf16.h>

// BilinearChebConv via Chebyshev-identity restructure:
//   T2 = 2L^2 - I, T3 = 2L*T2 - L, T4 = 2*T2^2 - I   (all symmetric)
//   Y_j = T_j(Lr) @ X   (one batched GEMM M=6144, B^T = X^T)
//   Z_{i,j} = Y_i @ T_j(Lc)  (one GEMM M=7680, N=6144, 2880 blocks)
//   out[o] = sum_ij theta[i,j,o] * Z_{i,j} + bias[o]
// All GEMM I/O bf16; no fp32 carry planes; 9 dispatches total.

#define NDIM 1536
#define PM (NDIM * NDIM)  // 2359296

typedef __attribute__((ext_vector_type(8))) short bf16x8;
typedef __attribute__((ext_vector_type(4))) float f32x4;

__device__ inline void gload_lds16(const void* g, void* l) {
  __builtin_amdgcn_global_load_lds(
      (const __attribute__((address_space(1))) void*)g,
      (__attribute__((address_space(3))) void*)l, 16, 0, 0);
}

__device__ inline unsigned short f2bf(float f) {
  __hip_bfloat16 h = __float2bfloat16(f);
  return *reinterpret_cast<unsigned short*>(&h);
}
__device__ inline float bf2f(unsigned short u) {
  return __uint_as_float((unsigned)u << 16);
}

struct ZSet {
  const unsigned short* A;   // M x 1536 row-major bf16
  const unsigned short* Bt;  // B^T rows (B symmetric => B rows), multi-plane via jn
  unsigned short* out;       // multi-plane via jn (stride 5*PM per j-plane-group)
  const unsigned short* Cp;  // mode 1 subtrahend
  int mode;                  // 0: A@B ; 1: 2*A@B - Cp ; 2: 2*A@B - I
};
struct ZSet4 { ZSet z[4]; };

// 128x128 tile, 4 waves (2x2), 16x16x32 bf16 MFMA, global_load_lds width-16.
__global__ __launch_bounds__(256) void gemm_k(ZSet4 zs) {
  const ZSet zp = zs.z[blockIdx.z];
  __shared__ __align__(16) unsigned short As[128 * 32];
  __shared__ __align__(16) unsigned short Bs[128 * 32];
  const int tid = threadIdx.x;
  const int lane = tid & 63;
  const int wave = tid >> 6;
  const int wm = wave >> 1, wn = wave & 1;
  const int gm0 = blockIdx.y * 128;
  const int jn = blockIdx.x / 12;             // which B/out plane along N
  const int nloc0 = (blockIdx.x % 12) * 128;  // col within plane
  const int q = lane >> 4;
  const int rowl = lane & 15;

  const unsigned short* Btb = zp.Bt + (size_t)jn * PM;
  unsigned short* outb = zp.out + (size_t)jn * 5 * PM;

  f32x4 acc[4][4] = {};

  for (int k0 = 0; k0 < NDIM; k0 += 32) {
#pragma unroll
    for (int l = 0; l < 2; ++l) {
      int f = l * 256 + wave * 64 + lane;  // 512 16B chunks per 128x32 tile
      int r = f >> 2, kc = f & 3;
      const unsigned short* ga = zp.A + (size_t)(gm0 + r) * NDIM + k0 + kc * 8;
      const unsigned short* gb = Btb + (size_t)(nloc0 + r) * NDIM + k0 + kc * 8;
      unsigned short* la = &As[(size_t)(l * 256 + wave * 64) * 8];
      unsigned short* lb = &Bs[(size_t)(l * 256 + wave * 64) * 8];
      gload_lds16(ga, la);
      gload_lds16(gb, lb);
    }
    __syncthreads();
    bf16x8 af[4], bfv[4];
#pragma unroll
    for (int t = 0; t < 4; ++t) {
      af[t] = *(const bf16x8*)&As[(wm * 64 + t * 16 + rowl) * 32 + q * 8];
      bfv[t] = *(const bf16x8*)&Bs[(wn * 64 + t * 16 + rowl) * 32 + q * 8];
    }
#pragma unroll
    for (int mt = 0; mt < 4; ++mt)
#pragma unroll
      for (int nt = 0; nt < 4; ++nt)
        acc[mt][nt] = __builtin_amdgcn_mfma_f32_16x16x32_bf16(
            af[mt], bfv[nt], acc[mt][nt], 0, 0, 0);
    __syncthreads();
  }

  // C/D layout: col = lane&15, row = (lane>>4)*4 + reg
#pragma unroll
  for (int mt = 0; mt < 4; ++mt) {
#pragma unroll
    for (int nt = 0; nt < 4; ++nt) {
#pragma unroll
      for (int v = 0; v < 4; ++v) {
        int row = gm0 + wm * 64 + mt * 16 + q * 4 + v;
        int col = nloc0 + wn * 64 + nt * 16 + rowl;
        size_t idx = (size_t)row * NDIM + col;
        float val = acc[mt][nt][v];
        if (zp.mode == 1) val = 2.0f * val - bf2f(zp.Cp[idx]);
        if (zp.mode == 2) val = 2.0f * val - (row == col ? 1.0f : 0.0f);
        outb[idx] = f2bf(val);
      }
    }
  }
}

// X^T: fp32 in -> bf16 out (transposed)
__global__ void transpose_f2b(const float* __restrict__ in,
                              unsigned short* __restrict__ out16) {
  __shared__ float tile[32][33];
  int bx = blockIdx.x, by = blockIdx.y;
  int tx = threadIdx.x;
#pragma unroll
  for (int r = threadIdx.y; r < 32; r += 8)
    tile[r][tx] = in[(size_t)(by * 32 + r) * NDIM + bx * 32 + tx];
  __syncthreads();
  int ox = by * 32 + tx;
#pragma unroll
  for (int r = threadIdx.y; r < 32; r += 8)
    out16[(size_t)(bx * 32 + r) * NDIM + ox] = f2bf(tile[tx][r]);
}

__global__ void cast_bf16_k(const float* __restrict__ in,
                            unsigned short* __restrict__ out) {
  int i = (blockIdx.x * 256 + threadIdx.x) * 4;
  float4 v = *(const float4*)(in + i);
  ushort4 r;
  r.x = f2bf(v.x); r.y = f2bf(v.y); r.z = f2bf(v.z); r.w = f2bf(v.w);
  *(ushort4*)(out + i) = r;
}

// Z: 25 bf16 planes, plane c = j*5+i. theta flat: i*160 + j*32 + o.
// 4 pixels per thread.
__global__ void combine_k(const unsigned short* __restrict__ Z,
                          const float* __restrict__ theta,
                          const float* __restrict__ bias,
                          float* __restrict__ out) {
  const size_t p0 = (size_t)(blockIdx.x * 256 + threadIdx.x) * 4;
  float z[25][4];
#pragma unroll
  for (int c = 0; c < 25; ++c) {
    uint2 u = *(const uint2*)(Z + (size_t)c * PM + p0);
    z[c][0] = __uint_as_float(u.x << 16);
    z[c][1] = __uint_as_float(u.x & 0xffff0000u);
    z[c][2] = __uint_as_float(u.y << 16);
    z[c][3] = __uint_as_float(u.y & 0xffff0000u);
  }
  for (int o = 0; o < 32; ++o) {
    float b = bias[o];
    float a0 = b, a1 = b, a2 = b, a3 = b;
#pragma unroll
    for (int j = 0; j < 5; ++j)
#pragma unroll
      for (int i = 0; i < 5; ++i) {
        float t = theta[i * 160 + j * 32 + o];  // wave-uniform -> scalar
        int c = j * 5 + i;
        a0 += t * z[c][0]; a1 += t * z[c][1];
        a2 += t * z[c][2]; a3 += t * z[c][3];
      }
    float4 w; w.x = a0; w.y = a1; w.z = a2; w.w = a3;
    *(float4*)(out + (size_t)o * PM + p0) = w;
  }
}

extern "C" void kernel_launch(void* const* d_in, const int* in_sizes, int n_in,
                              void* d_out, int out_size, void* d_ws, size_t ws_size,
                              hipStream_t stream) {
  (void)in_sizes; (void)n_in; (void)out_size; (void)ws_size;
  const float* X = (const float*)d_in[0];
  const float* Lr = (const float*)d_in[1];
  const float* Lc = (const float*)d_in[2];
  const float* theta = (const float*)d_in[3];
  const float* bias = (const float*)d_in[4];
  float* out = (float*)d_out;

  // Workspace: Zall(25) + Tr(4) + Tc(4) + Xt(1) = 34 bf16 planes = 160 MiB
  unsigned short* Zall = (unsigned short*)d_ws;      // plane c = j*5 + i
  unsigned short* Tr = Zall + (size_t)25 * PM;       // [Lr, T2r, T3r, T4r]
  unsigned short* Tc = Tr + (size_t)4 * PM;          // [Lc, T2c, T3c, T4c]
  unsigned short* Xt = Tc + (size_t)4 * PM;

  unsigned short* Tr0 = Tr;                 unsigned short* Tc0 = Tc;
  unsigned short* Tr1 = Tr + (size_t)PM;    unsigned short* Tc1 = Tc + (size_t)PM;
  unsigned short* Tr2 = Tr + (size_t)2*PM;  unsigned short* Tc2 = Tc + (size_t)2*PM;
  unsigned short* Tr3 = Tr + (size_t)3*PM;  unsigned short* Tc3 = Tc + (size_t)3*PM;

  cast_bf16_k<<<PM / 1024, 256, 0, stream>>>(Lr, Tr0);
  cast_bf16_k<<<PM / 1024, 256, 0, stream>>>(Lc, Tc0);
  cast_bf16_k<<<PM / 1024, 256, 0, stream>>>(X, Zall);           // Z[i=0,j=0] = X
  transpose_f2b<<<dim3(48, 48), dim3(32, 8), 0, stream>>>(X, Xt);

  // S1: T2r = 2*Lr@Lr - I ; T2c = 2*Lc@Lc - I      (z-batched)
  {
    ZSet4 a{};
    a.z[0] = {Tr0, Tr0, Tr1, nullptr, 2};
    a.z[1] = {Tc0, Tc0, Tc1, nullptr, 2};
    gemm_k<<<dim3(12, 12, 2), 256, 0, stream>>>(a);
  }
  // S2: T3 = 2*L@T2 - L ; T4 = 2*T2@T2 - I   (both axes, z-batched)
  {
    ZSet4 a{};
    a.z[0] = {Tr0, Tr1, Tr2, Tr0, 1};
    a.z[1] = {Tr1, Tr1, Tr3, nullptr, 2};
    a.z[2] = {Tc0, Tc1, Tc2, Tc0, 1};
    a.z[3] = {Tc1, Tc1, Tc3, nullptr, 2};
    gemm_k<<<dim3(12, 12, 4), 256, 0, stream>>>(a);
  }
  // G1: Y_j = T_j(Lr) @ X, j=1..4  -> Zall planes 1..4.  A = Tr stacked (M=6144),
  // B^T = Xt. N=1536 so jn==0.
  {
    ZSet4 a{};
    a.z[0] = {Tr, Xt, Zall + (size_t)PM, nullptr, 0};
    gemm_k<<<dim3(12, 48, 1), 256, 0, stream>>>(a);
  }
  // G2: Z_{i,j} = Y_i @ T_j(Lc). A = Zall[0..4] (M=7680), B planes via jn,
  // out plane group stride 5*PM -> Zall plane (1+jn)*5 + i.
  {
    ZSet4 a{};
    a.z[0] = {Zall, Tc0, Zall + (size_t)5 * PM, nullptr, 0};
    gemm_k<<<dim3(48, 60, 1), 256, 0, stream>>>(a);
  }

  combine_k<<<PM / 1024, 256, 0, stream>>>(Zall, theta, bias, out);
}

// Round 3
// 767.578 us; speedup vs baseline: 2.0324x; 2.0324x over previous
//
#include <hip/hip_runtime.h>
#include <hip/hip_bf16.h>

// BilinearChebConv via Chebyshev-identity restructure:
//   T2 = 2L^2 - I, T3 = 2L*T2 - L, T4 = 2*T2^2 - I   (all symmetric)
//   Y_j = T_j(Lr) @ X   (one batched GEMM M=6144, B^T = X^T)
//   Z_{i,j} = Y_i @ T_j(Lc)  (one GEMM M=7680, N=6144, 2880 blocks)
//   out[o] = sum_ij theta[i,j,o] * Z_{i,j} + bias[o]
// All GEMM I/O bf16; 9 dispatches.
// R3 fix: combine_k back to 2 px/thread + __launch_bounds__(256,2) — R2's
// 4 px/thread needed 100+ VGPRs but compiler clamped to 64 -> scratch spill
// (3.06 GB traffic, 912 us). 2 px fits in ~70 VGPRs.

#define NDIM 1536
#define PM (NDIM * NDIM)  // 2359296

typedef __attribute__((ext_vector_type(8))) short bf16x8;
typedef __attribute__((ext_vector_type(4))) float f32x4;

__device__ inline void gload_lds16(const void* g, void* l) {
  __builtin_amdgcn_global_load_lds(
      (const __attribute__((address_space(1))) void*)g,
      (__attribute__((address_space(3))) void*)l, 16, 0, 0);
}

__device__ inline unsigned short f2bf(float f) {
  __hip_bfloat16 h = __float2bfloat16(f);
  return *reinterpret_cast<unsigned short*>(&h);
}
__device__ inline float bf2f(unsigned short u) {
  return __uint_as_float((unsigned)u << 16);
}

struct ZSet {
  const unsigned short* A;   // M x 1536 row-major bf16
  const unsigned short* Bt;  // B^T rows (B symmetric => B rows), multi-plane via jn
  unsigned short* out;       // multi-plane via jn (stride 5*PM per j-plane-group)
  const unsigned short* Cp;  // mode 1 subtrahend
  int mode;                  // 0: A@B ; 1: 2*A@B - Cp ; 2: 2*A@B - I
};
struct ZSet4 { ZSet z[4]; };

// 128x128 tile, 4 waves (2x2), 16x16x32 bf16 MFMA, global_load_lds width-16.
__global__ __launch_bounds__(256) void gemm_k(ZSet4 zs) {
  const ZSet zp = zs.z[blockIdx.z];
  __shared__ __align__(16) unsigned short As[128 * 32];
  __shared__ __align__(16) unsigned short Bs[128 * 32];
  const int tid = threadIdx.x;
  const int lane = tid & 63;
  const int wave = tid >> 6;
  const int wm = wave >> 1, wn = wave & 1;
  const int gm0 = blockIdx.y * 128;
  const int jn = blockIdx.x / 12;             // which B/out plane along N
  const int nloc0 = (blockIdx.x % 12) * 128;  // col within plane
  const int q = lane >> 4;
  const int rowl = lane & 15;

  const unsigned short* Btb = zp.Bt + (size_t)jn * PM;
  unsigned short* outb = zp.out + (size_t)jn * 5 * PM;

  f32x4 acc[4][4] = {};

  for (int k0 = 0; k0 < NDIM; k0 += 32) {
#pragma unroll
    for (int l = 0; l < 2; ++l) {
      int f = l * 256 + wave * 64 + lane;  // 512 16B chunks per 128x32 tile
      int r = f >> 2, kc = f & 3;
      const unsigned short* ga = zp.A + (size_t)(gm0 + r) * NDIM + k0 + kc * 8;
      const unsigned short* gb = Btb + (size_t)(nloc0 + r) * NDIM + k0 + kc * 8;
      unsigned short* la = &As[(size_t)(l * 256 + wave * 64) * 8];
      unsigned short* lb = &Bs[(size_t)(l * 256 + wave * 64) * 8];
      gload_lds16(ga, la);
      gload_lds16(gb, lb);
    }
    __syncthreads();
    bf16x8 af[4], bfv[4];
#pragma unroll
    for (int t = 0; t < 4; ++t) {
      af[t] = *(const bf16x8*)&As[(wm * 64 + t * 16 + rowl) * 32 + q * 8];
      bfv[t] = *(const bf16x8*)&Bs[(wn * 64 + t * 16 + rowl) * 32 + q * 8];
    }
#pragma unroll
    for (int mt = 0; mt < 4; ++mt)
#pragma unroll
      for (int nt = 0; nt < 4; ++nt)
        acc[mt][nt] = __builtin_amdgcn_mfma_f32_16x16x32_bf16(
            af[mt], bfv[nt], acc[mt][nt], 0, 0, 0);
    __syncthreads();
  }

  // C/D layout: col = lane&15, row = (lane>>4)*4 + reg
#pragma unroll
  for (int mt = 0; mt < 4; ++mt) {
#pragma unroll
    for (int nt = 0; nt < 4; ++nt) {
#pragma unroll
      for (int v = 0; v < 4; ++v) {
        int row = gm0 + wm * 64 + mt * 16 + q * 4 + v;
        int col = nloc0 + wn * 64 + nt * 16 + rowl;
        size_t idx = (size_t)row * NDIM + col;
        float val = acc[mt][nt][v];
        if (zp.mode == 1) val = 2.0f * val - bf2f(zp.Cp[idx]);
        if (zp.mode == 2) val = 2.0f * val - (row == col ? 1.0f : 0.0f);
        outb[idx] = f2bf(val);
      }
    }
  }
}

// X^T: fp32 in -> bf16 out (transposed)
__global__ void transpose_f2b(const float* __restrict__ in,
                              unsigned short* __restrict__ out16) {
  __shared__ float tile[32][33];
  int bx = blockIdx.x, by = blockIdx.y;
  int tx = threadIdx.x;
#pragma unroll
  for (int r = threadIdx.y; r < 32; r += 8)
    tile[r][tx] = in[(size_t)(by * 32 + r) * NDIM + bx * 32 + tx];
  __syncthreads();
  int ox = by * 32 + tx;
#pragma unroll
  for (int r = threadIdx.y; r < 32; r += 8)
    out16[(size_t)(bx * 32 + r) * NDIM + ox] = f2bf(tile[tx][r]);
}

__global__ void cast_bf16_k(const float* __restrict__ in,
                            unsigned short* __restrict__ out) {
  int i = (blockIdx.x * 256 + threadIdx.x) * 4;
  float4 v = *(const float4*)(in + i);
  ushort4 r;
  r.x = f2bf(v.x); r.y = f2bf(v.y); r.z = f2bf(v.z); r.w = f2bf(v.w);
  *(ushort4*)(out + i) = r;
}

// Z: 25 bf16 planes, plane c = j*5+i. theta flat: i*160 + j*32 + o.
// 2 pixels per thread; ~70 live VGPRs — bounds (256,2) gives a 256-VGPR budget.
__global__ __launch_bounds__(256, 2) void combine_k(
    const unsigned short* __restrict__ Z,
    const float* __restrict__ theta,
    const float* __restrict__ bias,
    float* __restrict__ out) {
  const size_t p0 = (size_t)(blockIdx.x * 256 + threadIdx.x) * 2;
  float z0[25], z1[25];
#pragma unroll
  for (int c = 0; c < 25; ++c) {
    unsigned int u = *(const unsigned int*)(Z + (size_t)c * PM + p0);
    z0[c] = __uint_as_float(u << 16);
    z1[c] = __uint_as_float(u & 0xffff0000u);
  }
  for (int o = 0; o < 32; ++o) {
    float b = bias[o];
    float a0 = b, a1 = b;
#pragma unroll
    for (int j = 0; j < 5; ++j)
#pragma unroll
      for (int i = 0; i < 5; ++i) {
        float t = theta[i * 160 + j * 32 + o];  // wave-uniform -> s_load
        int c = j * 5 + i;
        a0 += t * z0[c];
        a1 += t * z1[c];
      }
    float2 w; w.x = a0; w.y = a1;
    *(float2*)(out + (size_t)o * PM + p0) = w;
  }
}

extern "C" void kernel_launch(void* const* d_in, const int* in_sizes, int n_in,
                              void* d_out, int out_size, void* d_ws, size_t ws_size,
                              hipStream_t stream) {
  (void)in_sizes; (void)n_in; (void)out_size; (void)ws_size;
  const float* X = (const float*)d_in[0];
  const float* Lr = (const float*)d_in[1];
  const float* Lc = (const float*)d_in[2];
  const float* theta = (const float*)d_in[3];
  const float* bias = (const float*)d_in[4];
  float* out = (float*)d_out;

  // Workspace: Zall(25) + Tr(4) + Tc(4) + Xt(1) = 34 bf16 planes = 160 MiB
  unsigned short* Zall = (unsigned short*)d_ws;      // plane c = j*5 + i
  unsigned short* Tr = Zall + (size_t)25 * PM;       // [Lr, T2r, T3r, T4r]
  unsigned short* Tc = Tr + (size_t)4 * PM;          // [Lc, T2c, T3c, T4c]
  unsigned short* Xt = Tc + (size_t)4 * PM;

  unsigned short* Tr0 = Tr;                 unsigned short* Tc0 = Tc;
  unsigned short* Tr1 = Tr + (size_t)PM;    unsigned short* Tc1 = Tc + (size_t)PM;
  unsigned short* Tr2 = Tr + (size_t)2*PM;  unsigned short* Tc2 = Tc + (size_t)2*PM;
  unsigned short* Tr3 = Tr + (size_t)3*PM;  unsigned short* Tc3 = Tc + (size_t)3*PM;

  cast_bf16_k<<<PM / 1024, 256, 0, stream>>>(Lr, Tr0);
  cast_bf16_k<<<PM / 1024, 256, 0, stream>>>(Lc, Tc0);
  cast_bf16_k<<<PM / 1024, 256, 0, stream>>>(X, Zall);           // Z[i=0,j=0] = X
  transpose_f2b<<<dim3(48, 48), dim3(32, 8), 0, stream>>>(X, Xt);

  // S1: T2r = 2*Lr@Lr - I ; T2c = 2*Lc@Lc - I      (z-batched)
  {
    ZSet4 a{};
    a.z[0] = {Tr0, Tr0, Tr1, nullptr, 2};
    a.z[1] = {Tc0, Tc0, Tc1, nullptr, 2};
    gemm_k<<<dim3(12, 12, 2), 256, 0, stream>>>(a);
  }
  // S2: T3 = 2*L@T2 - L ; T4 = 2*T2@T2 - I   (both axes, z-batched)
  {
    ZSet4 a{};
    a.z[0] = {Tr0, Tr1, Tr2, Tr0, 1};
    a.z[1] = {Tr1, Tr1, Tr3, nullptr, 2};
    a.z[2] = {Tc0, Tc1, Tc2, Tc0, 1};
    a.z[3] = {Tc1, Tc1, Tc3, nullptr, 2};
    gemm_k<<<dim3(12, 12, 4), 256, 0, stream>>>(a);
  }
  // G1: Y_j = T_j(Lr) @ X, j=1..4  -> Zall planes 1..4.  A = Tr stacked (M=6144),
  // B^T = Xt. N=1536 so jn==0.
  {
    ZSet4 a{};
    a.z[0] = {Tr, Xt, Zall + (size_t)PM, nullptr, 0};
    gemm_k<<<dim3(12, 48, 1), 256, 0, stream>>>(a);
  }
  // G2: Z_{i,j} = Y_i @ T_j(Lc). A = Zall[0..4] (M=7680), B planes via jn,
  // out plane group stride 5*PM -> Zall plane (1+jn)*5 + i.
  {
    ZSet4 a{};
    a.z[0] = {Zall, Tc0, Zall + (size_t)5 * PM, nullptr, 0};
    gemm_k<<<dim3(48, 60, 1), 256, 0, stream>>>(a);
  }

  combine_k<<<PM / 512, 256, 0, stream>>>(Zall, theta, bias, out);
}